// Round 6
// baseline (432.871 us; speedup 1.0000x reference)
//
#include <hip/hip_runtime.h>

typedef _Float16 h16;
typedef __attribute__((ext_vector_type(8))) _Float16 half8;
typedef __attribute__((ext_vector_type(4))) _Float16 half4;
typedef __attribute__((ext_vector_type(4))) float f32x4;
typedef __attribute__((ext_vector_type(16))) float f32x16;

// weight fragment offsets in d_ws (fp16 elements) — same conv format as R4/R5
constexpr size_t OFF_P0 = 0;        // [64 ][256]
constexpr size_t OFF_P1 = 16384;    // [256][256]
constexpr size_t OFF_P2 = 81920;
constexpr size_t OFF_P3 = 147456;
constexpr size_t OFF_P4 = 212992;
constexpr size_t OFF_P5 = 278528;   // [320][256], ROTATED: rows 0..255 = h-part, 256..319 = ep-part
constexpr size_t OFF_P6 = 360448;
constexpr size_t OFF_P7 = 425984;
constexpr size_t OFF_FEAT = 491520; // [256][256]
constexpr size_t OFF_VIEWS = 557056;// [288][128] (rows 0..255 feat, 256..282 ev, 283..287 zero)

__device__ __forceinline__ f32x16 mfma32(half8 a, half8 b, f32x16 c) {
  return __builtin_amdgcn_mfma_f32_32x32x16_f16(a, b, c, 0, 0, 0);
}
__device__ __forceinline__ half8 ldfrag(const h16* __restrict__ base, int frag, int l) {
  return *(const half8*)(base + (size_t)frag * 512 + (size_t)l * 8);
}
__device__ __forceinline__ half8 ldsfrag(const h16* __restrict__ base, int frag, int l) {
  return *(const half8*)(base + frag * 512 + l * 8);
}

// fp32 [K][N] row-major -> pre-swizzled fp16 fragments for 32x32x16 (unchanged).
__global__ void convw_kernel(const float* __restrict__ src, h16* __restrict__ dst,
                             int Ksrc, int N, int Kp, int p, int npad, int rot) {
  int t = blockIdx.x * 256 + threadIdx.x;
  int nfrags = (Kp >> 4) * (N >> 5);
  int frag = t >> 6;
  if (frag >= nfrags) return;
  int l = t & 63;
  int ntiles = N >> 5;
  int kt = frag / ntiles;
  int nt = frag - kt * ntiles;
  int col = nt * 32 + (l & 31);
  int kbase = kt * 16 + (l >> 5) * 8;
  half8 v;
#pragma unroll
  for (int j = 0; j < 8; ++j) {
    int pr = kbase + j + rot;
    if (pr >= Kp) pr -= Kp;
    float x = 0.f;
    if (pr < p) {
      x = src[(size_t)pr * N + col];
    } else if (pr >= p + npad) {
      int r = pr - npad;
      if (r < Ksrc) x = src[(size_t)r * N + col];
    }
    v[j] = (h16)x;
  }
  *(half8*)(dst + (size_t)frag * 512 + (size_t)l * 8) = v;
}

struct Params {
  const float* pts;
  const float* views;
  const h16* wf;
  const float* pb[8];
  const float* views_b;
  const float* feat_b;
  const float* alpha_w;
  const float* alpha_b;
  const float* rgb_w;
  const float* rgb_b;
  float* out;
};

// Epilogue: one 32x32 tile -> frag-major LDS.
// Element (row,col): frag=(row>>5)*16+(col>>4), lane=(row&31)+32*((col>>3)&1), elem=col&7.
template <bool RELU>
__device__ __forceinline__ void epiW(h16* __restrict__ Y, const f32x16& A,
                                     int rt, int ct, const float* __restrict__ bias,
                                     int lr, int lh) {
#pragma unroll
  for (int g = 0; g < 4; ++g) {
    int col0 = ct * 32 + g * 8 + lh * 4;
    f32x4 bv = *(const f32x4*)(bias + col0);
    half4 pk;
#pragma unroll
    for (int i = 0; i < 4; ++i) {
      float v = A[g * 4 + i] + bv[i];
      if (RELU) v = fmaxf(v, 0.f);
      pk[i] = (h16)v;
    }
    *(half4*)(Y + (rt * 16 + ct * 2 + (g >> 1)) * 512 + ((g & 1) * 32 + lr) * 8 + lh * 4) = pk;
  }
}

// One layer step, M=128, N=256. Wave w: row-tiles {2rp,2rp+1}, col-tiles {ctA,ctB}.
// Rolling depth-4 B-ring per col; refills load cur frag kt+4 or next layer's frag.
// EXTEP (L5): kt 16..19 read A from ep buffer (frag rt*4 + (kt-16)).
template <int KTTOT, int XSTRIDE, bool RELU, bool EXTEP>
__device__ __forceinline__ void layerT(
    const h16* __restrict__ X, const h16* __restrict__ EPb, h16* __restrict__ Y,
    const h16* __restrict__ wcur, const h16* __restrict__ wnext,
    int nstride, int nbA, int nbB, const float* __restrict__ bias,
    half8 (&rA)[4], half8 (&rB)[4], int rp, int ctA, int ctB, int l) {
  const int lr = l & 31, lh = l >> 5;
  f32x16 a00 = (f32x16)0.f, a01 = (f32x16)0.f, a10 = (f32x16)0.f, a11 = (f32x16)0.f;
#pragma unroll
  for (int kt = 0; kt < KTTOT; ++kt) {
    half8 x0, x1;
    if (!EXTEP || kt < 16) {
      x0 = ldsfrag(X, (2 * rp) * XSTRIDE + kt, l);
      x1 = ldsfrag(X, (2 * rp + 1) * XSTRIDE + kt, l);
    } else {
      x0 = ldsfrag(EPb, (2 * rp) * 4 + (kt - 16), l);
      x1 = ldsfrag(EPb, (2 * rp + 1) * 4 + (kt - 16), l);
    }
    half8 bA = rA[kt & 3], bB = rB[kt & 3];
    if (kt + 4 < KTTOT) {
      rA[kt & 3] = ldfrag(wcur, (kt + 4) * 8 + ctA, l);
      rB[kt & 3] = ldfrag(wcur, (kt + 4) * 8 + ctB, l);
    } else {
      rA[kt & 3] = ldfrag(wnext, (kt + 4 - KTTOT) * nstride + nbA, l);
      rB[kt & 3] = ldfrag(wnext, (kt + 4 - KTTOT) * nstride + nbB, l);
    }
    a00 = mfma32(bA, x0, a00);
    a01 = mfma32(bB, x0, a01);
    a10 = mfma32(bA, x1, a10);
    a11 = mfma32(bB, x1, a11);
  }
  epiW<RELU>(Y, a00, 2 * rp, ctA, bias, lr, lh);
  epiW<RELU>(Y, a01, 2 * rp, ctB, bias, lr, lh);
  epiW<RELU>(Y, a10, 2 * rp + 1, ctA, bias, lr, lh);
  epiW<RELU>(Y, a11, 2 * rp + 1, ctB, bias, lr, lh);
  __syncthreads();
}

__global__ __launch_bounds__(512, 2) void nerf_kernel(Params P) {
  __shared__ __align__(16) h16 ep[16 * 512];   // 16 KB, frag-major [rt*4+kt]
  __shared__ __align__(16) h16 h0[64 * 512];   // 64 KB, frag-major [rt*16+kt]
  __shared__ __align__(16) h16 h1[64 * 512];   // 64 KB
  __shared__ __align__(16) h16 evp[64];        // 2 rays x 32

  const int tid = threadIdx.x;
  const int w = tid >> 6, l = tid & 63;
  const int rp = w & 1, cp = w >> 1;
  const int ctA = 2 * cp, ctB = 2 * cp + 1;
  const h16* wf = P.wf;

  // prologue: fill B-ring with L0's 4 kt for both cols (latency hidden by embed)
  half8 rA[4], rB[4];
#pragma unroll
  for (int j = 0; j < 4; ++j) {
    rA[j] = ldfrag(wf + OFF_P0, j * 8 + ctA, l);
    rB[j] = ldfrag(wf + OFF_P0, j * 8 + ctB, l);
  }

  // ---- embeddings (fp32 math, fp16 frag-major store). 512 thr x 16 cols ----
  {
    const int s = tid >> 2, q = tid & 3;
    const float* ps = P.pts + ((size_t)blockIdx.x * 128 + s) * 3;
    const float x0 = ps[0], x1 = ps[1], x2 = ps[2];
    half8 v0, v1;
#pragma unroll
    for (int jj = 0; jj < 16; ++jj) {
      int p = q * 16 + jj;
      float val;
      if (p < 3) {
        val = p == 0 ? x0 : (p == 1 ? x1 : x2);
      } else if (p < 63) {
        int t = p - 3;
        int f = t / 6, rem = t % 6, d = rem % 3;
        float x = (d == 0 ? x0 : (d == 1 ? x1 : x2)) * (float)(1 << f);
        val = (rem < 3) ? sinf(x) : cosf(x);
      } else {
        val = 0.f;  // zero-pad col 63 (weight row 63 is zero too)
      }
      if (jj < 8) v0[jj] = (h16)val; else v1[jj - 8] = (h16)val;
    }
    int fr = (s >> 5) * 4 + q;
    *(half8*)(ep + fr * 512 + (s & 31) * 8) = v0;
    *(half8*)(ep + fr * 512 + (32 + (s & 31)) * 8) = v1;
  }
  if (tid < 64) {
    const int r = tid >> 5, idx = tid & 31;
    float v = 0.f;
    if (idx < 27) {
      if (idx < 3) {
        v = P.views[((size_t)blockIdx.x * 2 + r) * 3 + idx];
      } else {
        const int f = (idx - 3) / 6, rem = (idx - 3) % 6, d = rem % 3;
        const float x = P.views[((size_t)blockIdx.x * 2 + r) * 3 + d] * (float)(1 << f);
        v = (rem < 3) ? sinf(x) : cosf(x);
      }
    }
    evp[r * 32 + idx] = (h16)v;
  }
  __syncthreads();

  // ---- trunk (ping-pong h0/h1, 1 barrier/layer, continuous B stream) ----
  layerT<4, 4, true, false>(ep, ep, h0, wf + OFF_P0, wf + OFF_P1, 8, ctA, ctB, P.pb[0], rA, rB, rp, ctA, ctB, l);
  layerT<16, 16, true, false>(h0, ep, h1, wf + OFF_P1, wf + OFF_P2, 8, ctA, ctB, P.pb[1], rA, rB, rp, ctA, ctB, l);
  layerT<16, 16, true, false>(h1, ep, h0, wf + OFF_P2, wf + OFF_P3, 8, ctA, ctB, P.pb[2], rA, rB, rp, ctA, ctB, l);
  layerT<16, 16, true, false>(h0, ep, h1, wf + OFF_P3, wf + OFF_P4, 8, ctA, ctB, P.pb[3], rA, rB, rp, ctA, ctB, l);
  layerT<16, 16, true, false>(h1, ep, h0, wf + OFF_P4, wf + OFF_P5, 8, ctA, ctB, P.pb[4], rA, rB, rp, ctA, ctB, l);
  // L5: K=320 (16 kt from h0, 4 kt from ep; weights rotated h-part first)
  layerT<20, 16, true, true>(h0, ep, h1, wf + OFF_P5, wf + OFF_P6, 8, ctA, ctB, P.pb[5], rA, rB, rp, ctA, ctB, l);
  layerT<16, 16, true, false>(h1, ep, h0, wf + OFF_P6, wf + OFF_P7, 8, ctA, ctB, P.pb[6], rA, rB, rp, ctA, ctB, l);
  layerT<16, 16, true, false>(h0, ep, h1, wf + OFF_P7, wf + OFF_FEAT, 8, ctA, ctB, P.pb[7], rA, rB, rp, ctA, ctB, l);

  // ---- alpha = h1 @ alpha_w + alpha_b (no relu), frag-major reads ----
  float alpha_reg;
  {
    const int s = tid >> 2, q = tid & 3;
    float sum = 0.f;
#pragma unroll
    for (int j = 0; j < 8; ++j) {
      int k0 = q * 64 + j * 8;
      half8 hv = *(const half8*)(h1 + ((s >> 5) * 16 + (k0 >> 4)) * 512 +
                                 ((s & 31) + 32 * ((k0 >> 3) & 1)) * 8);
      f32x4 w0 = *(const f32x4*)(P.alpha_w + k0);
      f32x4 w1 = *(const f32x4*)(P.alpha_w + k0 + 4);
      sum += (float)hv[0] * w0[0] + (float)hv[1] * w0[1] + (float)hv[2] * w0[2] + (float)hv[3] * w0[3];
      sum += (float)hv[4] * w1[0] + (float)hv[5] * w1[1] + (float)hv[6] * w1[2] + (float)hv[7] * w1[3];
    }
    sum += __shfl_xor(sum, 1);
    sum += __shfl_xor(sum, 2);
    alpha_reg = sum + P.alpha_b[0];
  }

  // ---- feature = h1 @ feat_w + feat_b (no relu) -> h0; prefetch views frags ----
  layerT<16, 16, false, false>(h1, ep, h0, wf + OFF_FEAT, wf + OFF_VIEWS, 4,
                               2 * (w >> 2), 2 * (w >> 2) + 1, P.feat_b,
                               rA, rB, rp, ctA, ctB, l);

  // ---- h2 = relu([feature, ev] @ views_w + views_b) -> h1 frags [rt*16 + 0..7] ----
  // wave w: row-tile rt=w&3, col-tiles {2cv, 2cv+1}, cv=w>>2. K=288 (18 kt).
  {
    const int rt = w & 3, cv = w >> 2;
    const int vA = 2 * cv, vB = 2 * cv + 1;
    const int lr = l & 31, lh = l >> 5;
    const h16* wV = wf + OFF_VIEWS;
    f32x16 accA = (f32x16)0.f, accB = (f32x16)0.f;
#pragma unroll
    for (int kt = 0; kt < 18; ++kt) {
      half8 x;
      if (kt < 16) x = ldsfrag(h0, rt * 16 + kt, l);
      else x = *(const half8*)(evp + (rt >> 1) * 32 + (kt - 16) * 16 + lh * 8);
      half8 bA = rA[kt & 3], bB = rB[kt & 3];
      if (kt + 4 < 18) {
        rA[kt & 3] = ldfrag(wV, (kt + 4) * 4 + vA, l);
        rB[kt & 3] = ldfrag(wV, (kt + 4) * 4 + vB, l);
      }
      accA = mfma32(bA, x, accA);
      accB = mfma32(bB, x, accB);
    }
    epiW<true>(h1, accA, rt, vA, P.views_b, lr, lh);
    epiW<true>(h1, accB, rt, vB, P.views_b, lr, lh);
    __syncthreads();
  }

  // ---- rgb + output ----
  {
    const int s = tid >> 2, q = tid & 3;
    float r0 = 0.f, r1 = 0.f, r2 = 0.f;
#pragma unroll
    for (int j = 0; j < 4; ++j) {
      int k0 = q * 32 + j * 8;
      half8 hv = *(const half8*)(h1 + ((s >> 5) * 16 + (k0 >> 4)) * 512 +
                                 ((s & 31) + 32 * ((k0 >> 3) & 1)) * 8);
#pragma unroll
      for (int i = 0; i < 8; ++i) {
        const float f = (float)hv[i];
        r0 += f * P.rgb_w[(k0 + i) * 3 + 0];
        r1 += f * P.rgb_w[(k0 + i) * 3 + 1];
        r2 += f * P.rgb_w[(k0 + i) * 3 + 2];
      }
    }
    r0 += __shfl_xor(r0, 1); r0 += __shfl_xor(r0, 2);
    r1 += __shfl_xor(r1, 1); r1 += __shfl_xor(r1, 2);
    r2 += __shfl_xor(r2, 1); r2 += __shfl_xor(r2, 2);
    if (q == 0) {
      float4 o;
      o.x = r0 + P.rgb_b[0];
      o.y = r1 + P.rgb_b[1];
      o.z = r2 + P.rgb_b[2];
      o.w = alpha_reg;
      *(float4*)(P.out + ((size_t)blockIdx.x * 128 + s) * 4) = o;
    }
  }
}

extern "C" void kernel_launch(void* const* d_in, const int* in_sizes, int n_in,
                              void* d_out, int out_size, void* d_ws, size_t ws_size,
                              hipStream_t stream) {
  h16* wsw = (h16*)d_ws;
  auto conv = [&](int idx, int Ksrc, int N, int Kp, int p, int npad, int rot, size_t off) {
    int nfrags = (Kp / 16) * (N / 32);
    int total = nfrags * 64;
    convw_kernel<<<(total + 255) / 256, 256, 0, stream>>>(
        (const float*)d_in[idx], wsw + off, Ksrc, N, Kp, p, npad, rot);
  };
  conv(2, 63, 256, 64, 63, 1, 0, OFF_P0);
  conv(4, 256, 256, 256, 256, 0, 0, OFF_P1);
  conv(6, 256, 256, 256, 256, 0, 0, OFF_P2);
  conv(8, 256, 256, 256, 256, 0, 0, OFF_P3);
  conv(10, 256, 256, 256, 256, 0, 0, OFF_P4);
  conv(12, 319, 256, 320, 63, 1, 64, OFF_P5);   // rotated: h-part first
  conv(14, 256, 256, 256, 256, 0, 0, OFF_P6);
  conv(16, 256, 256, 256, 256, 0, 0, OFF_P7);
  conv(20, 256, 256, 256, 256, 0, 0, OFF_FEAT);
  conv(18, 283, 128, 288, 283, 5, 0, OFF_VIEWS);

  Params P;
  P.pts = (const float*)d_in[0];
  P.views = (const float*)d_in[1];
  P.wf = wsw;
  for (int i = 0; i < 8; ++i) P.pb[i] = (const float*)d_in[3 + 2 * i];
  P.views_b = (const float*)d_in[19];
  P.feat_b = (const float*)d_in[21];
  P.alpha_w = (const float*)d_in[22];
  P.alpha_b = (const float*)d_in[23];
  P.rgb_w = (const float*)d_in[24];
  P.rgb_b = (const float*)d_in[25];
  P.out = (float*)d_out;

  nerf_kernel<<<2048, 512, 0, stream>>>(P);
}